// Round 16
// baseline (160.657 us; speedup 1.0000x reference)
//
#include <hip/hip_runtime.h>
#include <hip/hip_bf16.h>
#include <math.h>

#define N_HEADS 4
#define D_HEAD 32
#define IN_DIM 256
#define OUT_DIM (N_HEADS * D_HEAD)   // 128
#define NEG_SLOPE 0.01f

// CSR-build geometry: 128 nodes per bucket, padded scratch regions.
// NOTE: packing (dst<<16 | src) requires n_nodes < 65536 (here 50000).
#define BSHIFT 7
#define BUCK_NODES 128
#define CAP 4096            // scratch slots per bucket (avg fill ~2048)
#define CHUNK 8192          // edges per bucketA block

typedef __attribute__((ext_vector_type(8))) short bf16x8;
typedef __attribute__((ext_vector_type(4))) float f32x4;
typedef __attribute__((ext_vector_type(2))) float f32x2;

// round-to-nearest-even f32 -> bf16 (as u16) — cold path only (setup)
static __device__ __forceinline__ unsigned short f2bf(float x)
{
    unsigned int u = __float_as_uint(x);
    u = u + 0x7FFFu + ((u >> 16) & 1u);
    return (unsigned short)(u >> 16);
}

// hot-path pack: 2 floats -> packed bf16x2 (v_cvt_pk_bf16_f32)
static __device__ __forceinline__ unsigned int pack_bf2(float a, float b)
{
    union { __hip_bfloat162 b2; unsigned int u; } r;
    r.b2 = __float22bfloat162_rn(make_float2(a, b));
    return r.u;
}

static __device__ __forceinline__ f32x2 bfpair(unsigned int u)
{
    f32x2 r;
    r.x = __uint_as_float(u << 16);
    r.y = __uint_as_float(u & 0xFFFF0000u);
    return r;
}

// ---------------------------------------------------------------------------
// setup: arrange fc_w into MFMA-B-fragment order (bf16); zero bucket_fill
// AND the A-completion counter (bucket_fill[nbuck]).
// ---------------------------------------------------------------------------
__global__ void setup_kernel(const float* __restrict__ fc_w,
                             unsigned short* __restrict__ wl,
                             int* __restrict__ bucket_fill, int nbuck)
{
    int o = blockIdx.x * blockDim.x + threadIdx.x;   // 0..32767
    if (o <= nbuck) bucket_fill[o] = 0;              // fills + ctrA
    if (o >= 32768) return;
    int j  = o & 7;
    int l  = (o >> 3) & 63;
    int kf = (o >> 9) & 7;
    int cf = (o >> 12) & 7;
    int k   = kf * 32 + (l >> 4) * 8 + j;
    int col = cf * 16 + (l & 15);
    int hh = col >> 5, d = col & 31;
    wl[o] = f2bf(fc_w[hh * 8192 + k * 32 + d]);
}

// ---------------------------------------------------------------------------
// MEGA kernel, three block ranges:
//   [0, nA)            : bucketA (CSR scatter, LDS-aggregated) -> ctrA++
//   [nA, nA+nG)        : MFMA GEMM (128 rows/block)
//   [nA+nG, +nbuck)    : bucketB — spin-waits ctrA==nA, then CSR finalize.
// Deadlock-safe: spinners (391) < co-residency capacity (512 blocks at
// 2/CU), and A/G blocks never wait, so A always progresses.
// 512 threads; 64 KB LDS union.
// ---------------------------------------------------------------------------
__global__ __launch_bounds__(512, 4) void mega_kernel(
    // gemm args
    const float* __restrict__ h, const unsigned short* __restrict__ wl,
    const float* __restrict__ attn_w,
    unsigned int* __restrict__ zb,
    float* __restrict__ s_src, float* __restrict__ s_dst,
    int n_nodes,
    // bucketA/B args
    const int* __restrict__ src, const int* __restrict__ dst,
    int* __restrict__ bucket_fill, unsigned int* __restrict__ scratch,
    int* __restrict__ row_start, int* __restrict__ sorted_src,
    int n_edges, int nbuck, int nA, int nG)
{
    __shared__ __align__(16) char smem[65536];
    const int t = threadIdx.x;

    if (blockIdx.x < nA) {
        // ----------------- bucketA path (512 threads) -----------------
        int* bhist = (int*)smem;                  //  2 KB
        int* boff  = (int*)(smem + 2048);         //  2 KB
        int* goff  = (int*)(smem + 4096);         //  2 KB
        int* bcur  = (int*)(smem + 6144);         //  2 KB
        int* stmp  = (int*)(smem + 8192);         //  2 KB
        unsigned int* lpair = (unsigned int*)(smem + 10240);   // 32 KB

        const int e0 = blockIdx.x * CHUNK;
        const int n  = min(CHUNK, n_edges - e0);

        bhist[t] = 0;
        __syncthreads();

        for (int i = t; i < n; i += 512) {
            atomicAdd(&bhist[dst[e0 + i] >> BSHIFT], 1);
        }
        __syncthreads();

        int v = bhist[t];
        int x = v;
        stmp[t] = x;
        __syncthreads();
        for (int off = 1; off < 512; off <<= 1) {
            int y = (t >= off) ? stmp[t - off] : 0;
            __syncthreads();
            x += y;
            stmp[t] = x;
            __syncthreads();
        }
        int excl = x - v;
        boff[t] = excl;
        bcur[t] = excl;

        goff[t] = (v > 0 && t < nbuck) ? (t * CAP + atomicAdd(&bucket_fill[t], v)) : 0;
        __syncthreads();

        for (int i = t; i < n; i += 512) {
            int d  = dst[e0 + i];
            int sv = src[e0 + i];
            int p  = atomicAdd(&bcur[d >> BSHIFT], 1);
            lpair[p] = ((unsigned int)d << 16) | (unsigned int)sv;
        }
        __syncthreads();

        const int lim = nbuck * CAP - 1;
        for (int i = t; i < n; i += 512) {
            unsigned int u = lpair[i];
            int b = (int)(u >> 16) >> BSHIFT;
            int addr = goff[b] + (i - boff[b]);
            scratch[min(addr, lim)] = u;
        }

        // publish: flush writes, then bump completion counter
        __syncthreads();
        __threadfence();
        if (t == 0) atomicAdd(&bucket_fill[nbuck], 1);
        return;
    }

    if (blockIdx.x < nA + nG) {
        // ----------------- gemm path (512 threads, 128 rows/block) -----------------
        unsigned short* wls = (unsigned short*)smem;   // 64 KB

        #pragma unroll
        for (int it = 0; it < 8; ++it) {
            ((uint4*)wls)[t + it * 512] = ((const uint4*)wl)[t + it * 512];
        }
        __syncthreads();

        const int w  = t >> 6;          // wave 0..7
        const int l  = t & 63;
        const int g  = l >> 4;
        const int ln = l & 15;
        const int m0 = (blockIdx.x - nA) * 128 + w * 16;

        const int arow = min(m0 + ln, n_nodes - 1);
        const float4* hrow = (const float4*)(h + (size_t)arow * IN_DIM);

        f32x4 acc[8];
        #pragma unroll
        for (int cf = 0; cf < 8; ++cf) acc[cf] = (f32x4){0.f, 0.f, 0.f, 0.f};

        #pragma unroll
        for (int kf = 0; kf < 8; ++kf) {
            float4 alo = hrow[kf * 8 + g * 2];
            float4 ahi = hrow[kf * 8 + g * 2 + 1];
            union { unsigned int u[4]; bf16x8 v; } fa;
            fa.u[0] = pack_bf2(alo.x, alo.y);
            fa.u[1] = pack_bf2(alo.z, alo.w);
            fa.u[2] = pack_bf2(ahi.x, ahi.y);
            fa.u[3] = pack_bf2(ahi.z, ahi.w);

            #pragma unroll
            for (int cf = 0; cf < 8; ++cf) {
                bf16x8 fb = *(const bf16x8*)&wls[((cf * 8 + kf) * 64 + l) * 8];
                acc[cf] = __builtin_amdgcn_mfma_f32_16x16x32_bf16(fa.v, fb, acc[cf], 0, 0, 0);
            }
        }

        float aw_s[8], aw_d[8];
        #pragma unroll
        for (int cf = 0; cf < 8; ++cf) {
            int col = cf * 16 + ln;
            int hh = col >> 5, d = col & 31;
            aw_s[cf] = attn_w[hh * 64 + d];
            aw_d[cf] = attn_w[hh * 64 + 32 + d];
        }

        #pragma unroll
        for (int r = 0; r < 4; ++r) {
            const int row = m0 + 4 * g + r;
            const bool ok = (row < n_nodes);

            float vs0 = acc[0][r] * aw_s[0] + acc[1][r] * aw_s[1];
            float vs1 = acc[2][r] * aw_s[2] + acc[3][r] * aw_s[3];
            float vs2 = acc[4][r] * aw_s[4] + acc[5][r] * aw_s[5];
            float vs3 = acc[6][r] * aw_s[6] + acc[7][r] * aw_s[7];
            float vd0 = acc[0][r] * aw_d[0] + acc[1][r] * aw_d[1];
            float vd1 = acc[2][r] * aw_d[2] + acc[3][r] * aw_d[3];
            float vd2 = acc[4][r] * aw_d[4] + acc[5][r] * aw_d[5];
            float vd3 = acc[6][r] * aw_d[6] + acc[7][r] * aw_d[7];
            #pragma unroll
            for (int mk = 1; mk < 16; mk <<= 1) {
                vs0 += __shfl_xor(vs0, mk); vs1 += __shfl_xor(vs1, mk);
                vs2 += __shfl_xor(vs2, mk); vs3 += __shfl_xor(vs3, mk);
                vd0 += __shfl_xor(vd0, mk); vd1 += __shfl_xor(vd1, mk);
                vd2 += __shfl_xor(vd2, mk); vd3 += __shfl_xor(vd3, mk);
            }
            float sel_s = (ln == 0) ? vs0 : (ln == 1) ? vs1 : (ln == 2) ? vs2 : vs3;
            float sel_d = ((ln & 3) == 0) ? vd0 : ((ln & 3) == 1) ? vd1 : ((ln & 3) == 2) ? vd2 : vd3;
            if (ok && ln < 4)              s_src[row * N_HEADS + ln]       = sel_s;
            if (ok && ln >= 4 && ln < 8)   s_dst[row * N_HEADS + (ln & 3)] = sel_d;

            #pragma unroll
            for (int cf = 0; cf < 8; ++cf) {
                float v = acc[cf][r];
                float o = __shfl_xor(v, 1);
                if (!(ln & 1) && ok) {
                    zb[(size_t)row * 64 + cf * 8 + (ln >> 1)] = pack_bf2(v, o);
                }
            }
        }
        return;
    }

    // ----------------- bucketB path (512 threads) -----------------
    {
        const int b = blockIdx.x - nA - nG;
        int* pref  = (int*)smem;                     // 2 KB (512)
        int* lhist = (int*)(smem + 2048);            // 512 B (128)
        int* lcur  = (int*)(smem + 2560);            // 512 B (128)
        int* stmp  = (int*)(smem + 4096);            // 2 KB (512)
        unsigned int* ent = (unsigned int*)(smem + 8192);   // 16 KB (CAP)

        // wait for all bucketA blocks (device-scope atomic poll + sleep)
        if (t == 0) {
            while (atomicAdd(&bucket_fill[nbuck], 0) < nA) {
                __builtin_amdgcn_s_sleep(2);
            }
        }
        __syncthreads();
        __threadfence();   // acquire: invalidate stale cached scratch lines

        // exclusive scan of bucket_fill -> pref (1 elem/thread over 512)
        {
            int v = (t < nbuck) ? min(bucket_fill[t], CAP) : 0;
            int x = v;
            stmp[t] = x;
            __syncthreads();
            for (int off = 1; off < 512; off <<= 1) {
                int y = (t >= off) ? stmp[t - off] : 0;
                __syncthreads();
                x += y;
                stmp[t] = x;
                __syncthreads();
            }
            pref[t] = x - v;
        }
        __syncthreads();

        const int cnt_b = min(bucket_fill[b], CAP);
        const int row0  = pref[b];
        const unsigned int* sb = scratch + (size_t)b * CAP;

        if (b == 0 && t == 0) row_start[n_nodes] = n_edges;

        if (t < 128) lhist[t] = 0;
        __syncthreads();

        for (int i = t; i < cnt_b; i += 512) {
            unsigned int u = sb[i];
            ent[i] = u;
            atomicAdd(&lhist[(u >> 16) & (BUCK_NODES - 1)], 1);
        }
        __syncthreads();

        int v = (t < 128) ? lhist[t] : 0;
        int x = v;
        if (t < 128) stmp[t] = x;
        __syncthreads();
        for (int off = 1; off < 128; off <<= 1) {
            int y = (t >= off && t < 128) ? stmp[t - off] : 0;
            __syncthreads();
            if (t < 128) { x += y; stmp[t] = x; }
            __syncthreads();
        }
        if (t < 128) {
            int excl = x - v;
            lcur[t] = excl;
            int node = b * BUCK_NODES + t;
            if (node < n_nodes) row_start[node] = row0 + excl;
        }
        __syncthreads();

        for (int i = t; i < cnt_b; i += 512) {
            unsigned int u = ent[i];
            int dl = (u >> 16) & (BUCK_NODES - 1);
            int r = atomicAdd(&lcur[dl], 1);
            sorted_src[row0 + r] = (int)(u & 0xFFFFu);
        }
    }
}

// ---------------------------------------------------------------------------
// fused single-pass softmax + aggregate. TWO nodes per wave:
// lanes 0-31 -> node 2*wid, lanes 32-63 -> node 2*wid+1.
// Per node: 2 edge slots (lane bit 4) x 4-deep unroll = 8 edges in flight.
// Lane owns 8 cols (uint4 of bf16x2).
// ---------------------------------------------------------------------------
__global__ __launch_bounds__(256) void gather_kernel(
    const int* __restrict__ sorted_src, const int* __restrict__ row_start,
    const unsigned int* __restrict__ zb,
    const float* __restrict__ s_src, const float* __restrict__ s_dst,
    float* __restrict__ out, int n_nodes)
{
    int wave = (blockIdx.x * 256 + threadIdx.x) >> 6;
    int lane = threadIdx.x & 63;
    int half = lane >> 5;
    int node = wave * 2 + half;
    int g2   = (lane >> 4) & 1;      // edge slot 0..1
    int q    = lane & 15;            // col group: cols 8q..8q+7
    int hh   = q >> 2;               // head

    const bool valid = (node < n_nodes);
    const int nclamp = min(node, n_nodes - 1);
    const int b0 = row_start[nclamp];
    int deg = row_start[nclamp + 1] - b0;
    if (!valid) deg = 0;

    f32x2 acc2[4];
    #pragma unroll
    for (int i = 0; i < 4; ++i) acc2[i] = (f32x2){0.f, 0.f};
    float den = 0.0f;

    if (deg > 0) {
        const int* sp = sorted_src + b0;
        const float sdst = s_dst[nclamp * N_HEADS + hh];
        const int dm1 = deg - 1;

        for (int p = 0; p < deg; p += 8) {
            int i0 = p + g2, i1 = p + 2 + g2, i2 = p + 4 + g2, i3 = p + 6 + g2;
            int s0 = sp[min(i0, dm1)];
            int s1 = sp[min(i1, dm1)];
            int s2 = sp[min(i2, dm1)];
            int s3 = sp[min(i3, dm1)];

            float f0 = s_src[s0 * N_HEADS + hh];
            float f1 = s_src[s1 * N_HEADS + hh];
            float f2 = s_src[s2 * N_HEADS + hh];
            float f3 = s_src[s3 * N_HEADS + hh];
            uint4 u0 = *(const uint4*)&zb[(size_t)s0 * 64 + q * 4];
            uint4 u1 = *(const uint4*)&zb[(size_t)s1 * 64 + q * 4];
            uint4 u2 = *(const uint4*)&zb[(size_t)s2 * 64 + q * 4];
            uint4 u3 = *(const uint4*)&zb[(size_t)s3 * 64 + q * 4];

            float e0 = f0 + sdst; e0 = fmaxf(e0, NEG_SLOPE * e0);
            float e1 = f1 + sdst; e1 = fmaxf(e1, NEG_SLOPE * e1);
            float e2 = f2 + sdst; e2 = fmaxf(e2, NEG_SLOPE * e2);
            float e3 = f3 + sdst; e3 = fmaxf(e3, NEG_SLOPE * e3);
            float x0 = (i0 <= dm1) ? __expf(e0) : 0.0f;
            float x1 = (i1 <= dm1) ? __expf(e1) : 0.0f;
            float x2 = (i2 <= dm1) ? __expf(e2) : 0.0f;
            float x3 = (i3 <= dm1) ? __expf(e3) : 0.0f;
            den += (x0 + x1) + (x2 + x3);

            f32x2 xv;
            xv = (f32x2){x0, x0};
            acc2[0] += xv * bfpair(u0.x);
            acc2[1] += xv * bfpair(u0.y);
            acc2[2] += xv * bfpair(u0.z);
            acc2[3] += xv * bfpair(u0.w);
            xv = (f32x2){x1, x1};
            acc2[0] += xv * bfpair(u1.x);
            acc2[1] += xv * bfpair(u1.y);
            acc2[2] += xv * bfpair(u1.z);
            acc2[3] += xv * bfpair(u1.w);
            xv = (f32x2){x2, x2};
            acc2[0] += xv * bfpair(u2.x);
            acc2[1] += xv * bfpair(u2.y);
            acc2[2] += xv * bfpair(u2.z);
            acc2[3] += xv * bfpair(u2.w);
            xv = (f32x2){x3, x3};
            acc2[0] += xv * bfpair(u3.x);
            acc2[1] += xv * bfpair(u3.y);
            acc2[2] += xv * bfpair(u3.z);
            acc2[3] += xv * bfpair(u3.w);
        }
    }

    // reduce across the 2 edge slots (lane bit 4; stays within 32-lane half)
    #pragma unroll
    for (int i = 0; i < 4; ++i) {
        acc2[i].x += __shfl_xor(acc2[i].x, 16);
        acc2[i].y += __shfl_xor(acc2[i].y, 16);
    }
    den += __shfl_xor(den, 16);

    if (g2 == 0 && valid) {
        float inv = (deg > 0) ? 1.0f / den : 0.0f;
        float4 v0 = make_float4(acc2[0].x * inv, acc2[0].y * inv, acc2[1].x * inv, acc2[1].y * inv);
        float4 v1 = make_float4(acc2[2].x * inv, acc2[2].y * inv, acc2[3].x * inv, acc2[3].y * inv);
        float4* op = (float4*)&out[(size_t)node * OUT_DIM + q * 8];
        op[0] = v0;
        op[1] = v1;
    }
}

// ---------------------------------------------------------------------------
extern "C" void kernel_launch(void* const* d_in, const int* in_sizes, int n_in,
                              void* d_out, int out_size, void* d_ws, size_t ws_size,
                              hipStream_t stream)
{
    const float* h      = (const float*)d_in[0];
    const float* fc_w   = (const float*)d_in[1];
    const float* attn_w = (const float*)d_in[2];
    const int*   src    = (const int*)d_in[3];
    const int*   dst    = (const int*)d_in[4];

    const int n_nodes = in_sizes[0] / IN_DIM;   // 50000
    const int n_edges = in_sizes[3];            // 800000
    const int nbuck   = (n_nodes + BUCK_NODES - 1) / BUCK_NODES;   // 391

    float* out = (float*)d_out;

    // workspace layout (all 4-byte types, 16B-aligned blocks)
    char* ws = (char*)d_ws;
    unsigned int* zb      = (unsigned int*)ws;                          // n_nodes*64 u32
    float* s_src          = (float*)(zb + (size_t)n_nodes * 64);        // n_nodes*4
    float* s_dst          = s_src + (size_t)n_nodes * N_HEADS;          // n_nodes*4
    int*   row_start      = (int*)(s_dst + (size_t)n_nodes * N_HEADS);  // n_nodes+1 (+pad)
    int*   bucket_fill    = row_start + n_nodes + 16;                   // nbuck + 1 (ctrA at [nbuck])
    int*   sorted_src     = bucket_fill + nbuck + 17;                   // n_edges
    unsigned int* scratch = (unsigned int*)(sorted_src + n_edges + 16); // nbuck*CAP
    unsigned short* wl_g  = (unsigned short*)(scratch + (size_t)nbuck * CAP); // 32768 bf16

    const int nA = (n_edges + CHUNK - 1) / CHUNK;        // 98 bucketA blocks
    const int nG = (n_nodes + 127) / 128;                // 391 gemm blocks

    // 1. setup: W prep + zero bucket_fill and ctrA
    setup_kernel<<<128, 256, 0, stream>>>(fc_w, wl_g, bucket_fill, nbuck);

    // 2. MEGA: bucketA ∥ MFMA GEMM ∥ bucketB(spin-on-A)
    mega_kernel<<<nA + nG + nbuck, 512, 0, stream>>>(
        h, wl_g, attn_w, zb, s_src, s_dst, n_nodes,
        src, dst, bucket_fill, scratch, row_start, sorted_src,
        n_edges, nbuck, nA, nG);

    // 3. fused single-pass softmax + aggregate, 2 consecutive nodes per wave
    {
        int waves = (n_nodes + 1) / 2;
        int blocks = (waves * 64 + 255) / 256;
        gather_kernel<<<blocks, 256, 0, stream>>>(
            sorted_src, row_start, zb, s_src, s_dst, out, n_nodes);
    }
}

// Round 17
// 70.888 us; speedup vs baseline: 2.2664x; 2.2664x over previous
//
#include <hip/hip_runtime.h>
#include <hip/hip_bf16.h>
#include <math.h>

#define N_HEADS 4
#define D_HEAD 32
#define IN_DIM 256
#define OUT_DIM (N_HEADS * D_HEAD)   // 128
#define NEG_SLOPE 0.01f

// CSR-build geometry: 128 nodes per bucket, padded scratch regions.
// NOTE: packing (dst<<16 | src) requires n_nodes < 65536 (here 50000).
#define BSHIFT 7
#define BUCK_NODES 128
#define CAP 4096            // scratch slots per bucket (avg fill ~2048)
#define CHUNK 8192          // edges per bucketA block

typedef __attribute__((ext_vector_type(8))) short bf16x8;
typedef __attribute__((ext_vector_type(4))) float f32x4;
typedef __attribute__((ext_vector_type(2))) float f32x2;

// round-to-nearest-even f32 -> bf16 (as u16) — cold path only (setup)
static __device__ __forceinline__ unsigned short f2bf(float x)
{
    unsigned int u = __float_as_uint(x);
    u = u + 0x7FFFu + ((u >> 16) & 1u);
    return (unsigned short)(u >> 16);
}

// hot-path pack: 2 floats -> packed bf16x2 (v_cvt_pk_bf16_f32)
static __device__ __forceinline__ unsigned int pack_bf2(float a, float b)
{
    union { __hip_bfloat162 b2; unsigned int u; } r;
    r.b2 = __float22bfloat162_rn(make_float2(a, b));
    return r.u;
}

static __device__ __forceinline__ f32x2 bfpair(unsigned int u)
{
    f32x2 r;
    r.x = __uint_as_float(u << 16);
    r.y = __uint_as_float(u & 0xFFFF0000u);
    return r;
}

// ---------------------------------------------------------------------------
// setup: arrange fc_w into MFMA-B-fragment order (bf16); zero bucket_fill.
// wl[((cf*8+kf)*64 + l)*8 + j] = B[kf*32 + 8*(l>>4) + j][cf*16 + (l&15)]
// ---------------------------------------------------------------------------
__global__ void setup_kernel(const float* __restrict__ fc_w,
                             unsigned short* __restrict__ wl,
                             int* __restrict__ bucket_fill, int nbuck)
{
    int o = blockIdx.x * blockDim.x + threadIdx.x;   // 0..32767
    if (o < nbuck) bucket_fill[o] = 0;
    if (o >= 32768) return;
    int j  = o & 7;
    int l  = (o >> 3) & 63;
    int kf = (o >> 9) & 7;
    int cf = (o >> 12) & 7;
    int k   = kf * 32 + (l >> 4) * 8 + j;
    int col = cf * 16 + (l & 15);
    int hh = col >> 5, d = col & 31;
    wl[o] = f2bf(fc_w[hh * 8192 + k * 32 + d]);
}

// ---------------------------------------------------------------------------
// FUSED kernel: blocks [0, nA) run bucketA (CSR scatter, LDS-aggregated);
// blocks [nA, nA+nG) run the MFMA GEMM (128 rows/block). The two phases are
// data-independent; fusing them lets the CSR work hide under the GEMM's
// latency slack instead of serializing on the stream.
// 512 threads; 64 KB LDS union.
// ---------------------------------------------------------------------------
__global__ __launch_bounds__(512, 4) void fused_kernel(
    // gemm args
    const float* __restrict__ h, const unsigned short* __restrict__ wl,
    const float* __restrict__ attn_w,
    unsigned int* __restrict__ zb,
    float* __restrict__ s_src, float* __restrict__ s_dst,
    int n_nodes,
    // bucketA args
    const int* __restrict__ src, const int* __restrict__ dst,
    int* __restrict__ bucket_fill, unsigned int* __restrict__ scratch,
    int n_edges, int nbuck, int nA)
{
    __shared__ __align__(16) char smem[65536];
    const int t = threadIdx.x;

    if (blockIdx.x < nA) {
        // ----------------- bucketA path (512 threads) -----------------
        int* bhist = (int*)smem;                  //  2 KB
        int* boff  = (int*)(smem + 2048);         //  2 KB
        int* goff  = (int*)(smem + 4096);         //  2 KB
        int* bcur  = (int*)(smem + 6144);         //  2 KB
        int* stmp  = (int*)(smem + 8192);         //  2 KB
        unsigned int* lpair = (unsigned int*)(smem + 10240);   // 32 KB

        const int e0 = blockIdx.x * CHUNK;
        const int n  = min(CHUNK, n_edges - e0);

        bhist[t] = 0;
        __syncthreads();

        for (int i = t; i < n; i += 512) {
            atomicAdd(&bhist[dst[e0 + i] >> BSHIFT], 1);
        }
        __syncthreads();

        // exclusive scan over 512 bins, 1 elem/thread
        int v = bhist[t];
        int x = v;
        stmp[t] = x;
        __syncthreads();
        for (int off = 1; off < 512; off <<= 1) {
            int y = (t >= off) ? stmp[t - off] : 0;
            __syncthreads();
            x += y;
            stmp[t] = x;
            __syncthreads();
        }
        int excl = x - v;
        boff[t] = excl;
        bcur[t] = excl;

        // reserve global space (one atomic per non-empty bucket)
        goff[t] = (v > 0 && t < nbuck) ? (t * CAP + atomicAdd(&bucket_fill[t], v)) : 0;
        __syncthreads();

        // stage pairs into LDS grouped by bucket
        for (int i = t; i < n; i += 512) {
            int d  = dst[e0 + i];
            int sv = src[e0 + i];
            int p  = atomicAdd(&bcur[d >> BSHIFT], 1);
            lpair[p] = ((unsigned int)d << 16) | (unsigned int)sv;
        }
        __syncthreads();

        // dense write-out
        const int lim = nbuck * CAP - 1;
        for (int i = t; i < n; i += 512) {
            unsigned int u = lpair[i];
            int b = (int)(u >> 16) >> BSHIFT;
            int addr = goff[b] + (i - boff[b]);
            scratch[min(addr, lim)] = u;
        }
        return;
    }

    // ----------------- gemm path (512 threads, 128 rows/block) -----------------
    unsigned short* wls = (unsigned short*)smem;   // 64 KB

    #pragma unroll
    for (int it = 0; it < 8; ++it) {
        ((uint4*)wls)[t + it * 512] = ((const uint4*)wl)[t + it * 512];
    }
    __syncthreads();

    const int w  = t >> 6;          // wave 0..7
    const int l  = t & 63;
    const int g  = l >> 4;
    const int ln = l & 15;
    const int m0 = (blockIdx.x - nA) * 128 + w * 16;

    const int arow = min(m0 + ln, n_nodes - 1);
    const float4* hrow = (const float4*)(h + (size_t)arow * IN_DIM);

    f32x4 acc[8];
    #pragma unroll
    for (int cf = 0; cf < 8; ++cf) acc[cf] = (f32x4){0.f, 0.f, 0.f, 0.f};

    #pragma unroll
    for (int kf = 0; kf < 8; ++kf) {
        float4 alo = hrow[kf * 8 + g * 2];
        float4 ahi = hrow[kf * 8 + g * 2 + 1];
        union { unsigned int u[4]; bf16x8 v; } fa;
        fa.u[0] = pack_bf2(alo.x, alo.y);
        fa.u[1] = pack_bf2(alo.z, alo.w);
        fa.u[2] = pack_bf2(ahi.x, ahi.y);
        fa.u[3] = pack_bf2(ahi.z, ahi.w);

        #pragma unroll
        for (int cf = 0; cf < 8; ++cf) {
            bf16x8 fb = *(const bf16x8*)&wls[((cf * 8 + kf) * 64 + l) * 8];
            acc[cf] = __builtin_amdgcn_mfma_f32_16x16x32_bf16(fa.v, fb, acc[cf], 0, 0, 0);
        }
    }

    float aw_s[8], aw_d[8];
    #pragma unroll
    for (int cf = 0; cf < 8; ++cf) {
        int col = cf * 16 + ln;
        int hh = col >> 5, d = col & 31;
        aw_s[cf] = attn_w[hh * 64 + d];
        aw_d[cf] = attn_w[hh * 64 + 32 + d];
    }

    #pragma unroll
    for (int r = 0; r < 4; ++r) {
        const int row = m0 + 4 * g + r;
        const bool ok = (row < n_nodes);

        float vs0 = acc[0][r] * aw_s[0] + acc[1][r] * aw_s[1];
        float vs1 = acc[2][r] * aw_s[2] + acc[3][r] * aw_s[3];
        float vs2 = acc[4][r] * aw_s[4] + acc[5][r] * aw_s[5];
        float vs3 = acc[6][r] * aw_s[6] + acc[7][r] * aw_s[7];
        float vd0 = acc[0][r] * aw_d[0] + acc[1][r] * aw_d[1];
        float vd1 = acc[2][r] * aw_d[2] + acc[3][r] * aw_d[3];
        float vd2 = acc[4][r] * aw_d[4] + acc[5][r] * aw_d[5];
        float vd3 = acc[6][r] * aw_d[6] + acc[7][r] * aw_d[7];
        #pragma unroll
        for (int mk = 1; mk < 16; mk <<= 1) {
            vs0 += __shfl_xor(vs0, mk); vs1 += __shfl_xor(vs1, mk);
            vs2 += __shfl_xor(vs2, mk); vs3 += __shfl_xor(vs3, mk);
            vd0 += __shfl_xor(vd0, mk); vd1 += __shfl_xor(vd1, mk);
            vd2 += __shfl_xor(vd2, mk); vd3 += __shfl_xor(vd3, mk);
        }
        float sel_s = (ln == 0) ? vs0 : (ln == 1) ? vs1 : (ln == 2) ? vs2 : vs3;
        float sel_d = ((ln & 3) == 0) ? vd0 : ((ln & 3) == 1) ? vd1 : ((ln & 3) == 2) ? vd2 : vd3;
        if (ok && ln < 4)              s_src[row * N_HEADS + ln]       = sel_s;
        if (ok && ln >= 4 && ln < 8)   s_dst[row * N_HEADS + (ln & 3)] = sel_d;

        #pragma unroll
        for (int cf = 0; cf < 8; ++cf) {
            float v = acc[cf][r];
            float o = __shfl_xor(v, 1);
            if (!(ln & 1) && ok) {
                zb[(size_t)row * 64 + cf * 8 + (ln >> 1)] = pack_bf2(v, o);
            }
        }
    }
}

// ---------------------------------------------------------------------------
// Pass B: one block per bucket, pure LDS work + dense writes. Redundant
// bucket scan -> row0; per-node LDS histogram + scan -> row_start; placement
// writes plain src into sorted_src.
// ---------------------------------------------------------------------------
__global__ __launch_bounds__(256) void bucketB_kernel(
    const unsigned int* __restrict__ scratch,
    const int* __restrict__ bucket_fill,
    int* __restrict__ row_start,
    int* __restrict__ sorted_src,
    int n_nodes, int nbuck, int n_edges)
{
    __shared__ int pref[512];
    __shared__ int lhist[128];
    __shared__ int lcur[128];
    __shared__ int stmp[256];
    __shared__ unsigned int ent[CAP];   // 16 KB

    const int b = blockIdx.x;
    const int t = threadIdx.x;

    // --- redundant exclusive scan of bucket_fill -> pref[] ---
    {
        int a0 = (2 * t     < nbuck) ? min(bucket_fill[2 * t],     CAP) : 0;
        int a1 = (2 * t + 1 < nbuck) ? min(bucket_fill[2 * t + 1], CAP) : 0;
        int s = a0 + a1;
        int x = s;
        stmp[t] = x;
        __syncthreads();
        for (int off = 1; off < 256; off <<= 1) {
            int y = (t >= off) ? stmp[t - off] : 0;
            __syncthreads();
            x += y;
            stmp[t] = x;
            __syncthreads();
        }
        int excl = x - s;
        pref[2 * t]     = excl;
        pref[2 * t + 1] = excl + a0;
    }
    __syncthreads();

    const int cnt_b = min(bucket_fill[b], CAP);
    const int row0  = pref[b];
    const unsigned int* sb = scratch + (size_t)b * CAP;

    if (b == 0 && t == 0) row_start[n_nodes] = n_edges;

    if (t < 128) lhist[t] = 0;
    __syncthreads();

    for (int i = t; i < cnt_b; i += 256) {
        unsigned int u = sb[i];
        ent[i] = u;
        atomicAdd(&lhist[(u >> 16) & (BUCK_NODES - 1)], 1);
    }
    __syncthreads();

    int v = (t < 128) ? lhist[t] : 0;
    int x = v;
    stmp[t] = x;
    __syncthreads();
    for (int off = 1; off < 128; off <<= 1) {
        int y = (t >= off) ? stmp[t - off] : 0;
        __syncthreads();
        x += y;
        stmp[t] = x;
        __syncthreads();
    }
    if (t < 128) {
        int excl = x - v;
        lcur[t] = excl;
        int node = b * BUCK_NODES + t;
        if (node < n_nodes) row_start[node] = row0 + excl;
    }
    __syncthreads();

    for (int i = t; i < cnt_b; i += 256) {
        unsigned int u = ent[i];
        int dl = (u >> 16) & (BUCK_NODES - 1);
        int r = atomicAdd(&lcur[dl], 1);
        sorted_src[row0 + r] = (int)(u & 0xFFFFu);
    }
}

// ---------------------------------------------------------------------------
// fused single-pass softmax + aggregate. TWO nodes per wave:
// lanes 0-31 -> node 2*wid, lanes 32-63 -> node 2*wid+1.
// Per node: 2 edge slots (lane bit 4) x 4-deep unroll = 8 edges in flight.
// Lane owns 8 cols (uint4 of bf16x2).
// ---------------------------------------------------------------------------
__global__ __launch_bounds__(256) void gather_kernel(
    const int* __restrict__ sorted_src, const int* __restrict__ row_start,
    const unsigned int* __restrict__ zb,
    const float* __restrict__ s_src, const float* __restrict__ s_dst,
    float* __restrict__ out, int n_nodes)
{
    int wave = (blockIdx.x * 256 + threadIdx.x) >> 6;
    int lane = threadIdx.x & 63;
    int half = lane >> 5;
    int node = wave * 2 + half;
    int g2   = (lane >> 4) & 1;      // edge slot 0..1
    int q    = lane & 15;            // col group: cols 8q..8q+7
    int hh   = q >> 2;               // head

    const bool valid = (node < n_nodes);
    const int nclamp = min(node, n_nodes - 1);
    const int b0 = row_start[nclamp];
    int deg = row_start[nclamp + 1] - b0;
    if (!valid) deg = 0;

    f32x2 acc2[4];
    #pragma unroll
    for (int i = 0; i < 4; ++i) acc2[i] = (f32x2){0.f, 0.f};
    float den = 0.0f;

    if (deg > 0) {
        const int* sp = sorted_src + b0;
        const float sdst = s_dst[nclamp * N_HEADS + hh];
        const int dm1 = deg - 1;

        for (int p = 0; p < deg; p += 8) {
            int i0 = p + g2, i1 = p + 2 + g2, i2 = p + 4 + g2, i3 = p + 6 + g2;
            int s0 = sp[min(i0, dm1)];
            int s1 = sp[min(i1, dm1)];
            int s2 = sp[min(i2, dm1)];
            int s3 = sp[min(i3, dm1)];

            float f0 = s_src[s0 * N_HEADS + hh];
            float f1 = s_src[s1 * N_HEADS + hh];
            float f2 = s_src[s2 * N_HEADS + hh];
            float f3 = s_src[s3 * N_HEADS + hh];
            uint4 u0 = *(const uint4*)&zb[(size_t)s0 * 64 + q * 4];
            uint4 u1 = *(const uint4*)&zb[(size_t)s1 * 64 + q * 4];
            uint4 u2 = *(const uint4*)&zb[(size_t)s2 * 64 + q * 4];
            uint4 u3 = *(const uint4*)&zb[(size_t)s3 * 64 + q * 4];

            float e0 = f0 + sdst; e0 = fmaxf(e0, NEG_SLOPE * e0);
            float e1 = f1 + sdst; e1 = fmaxf(e1, NEG_SLOPE * e1);
            float e2 = f2 + sdst; e2 = fmaxf(e2, NEG_SLOPE * e2);
            float e3 = f3 + sdst; e3 = fmaxf(e3, NEG_SLOPE * e3);
            float x0 = (i0 <= dm1) ? __expf(e0) : 0.0f;
            float x1 = (i1 <= dm1) ? __expf(e1) : 0.0f;
            float x2 = (i2 <= dm1) ? __expf(e2) : 0.0f;
            float x3 = (i3 <= dm1) ? __expf(e3) : 0.0f;
            den += (x0 + x1) + (x2 + x3);

            f32x2 xv;
            xv = (f32x2){x0, x0};
            acc2[0] += xv * bfpair(u0.x);
            acc2[1] += xv * bfpair(u0.y);
            acc2[2] += xv * bfpair(u0.z);
            acc2[3] += xv * bfpair(u0.w);
            xv = (f32x2){x1, x1};
            acc2[0] += xv * bfpair(u1.x);
            acc2[1] += xv * bfpair(u1.y);
            acc2[2] += xv * bfpair(u1.z);
            acc2[3] += xv * bfpair(u1.w);
            xv = (f32x2){x2, x2};
            acc2[0] += xv * bfpair(u2.x);
            acc2[1] += xv * bfpair(u2.y);
            acc2[2] += xv * bfpair(u2.z);
            acc2[3] += xv * bfpair(u2.w);
            xv = (f32x2){x3, x3};
            acc2[0] += xv * bfpair(u3.x);
            acc2[1] += xv * bfpair(u3.y);
            acc2[2] += xv * bfpair(u3.z);
            acc2[3] += xv * bfpair(u3.w);
        }
    }

    // reduce across the 2 edge slots (lane bit 4; stays within 32-lane half)
    #pragma unroll
    for (int i = 0; i < 4; ++i) {
        acc2[i].x += __shfl_xor(acc2[i].x, 16);
        acc2[i].y += __shfl_xor(acc2[i].y, 16);
    }
    den += __shfl_xor(den, 16);

    if (g2 == 0 && valid) {
        float inv = (deg > 0) ? 1.0f / den : 0.0f;
        float4 v0 = make_float4(acc2[0].x * inv, acc2[0].y * inv, acc2[1].x * inv, acc2[1].y * inv);
        float4 v1 = make_float4(acc2[2].x * inv, acc2[2].y * inv, acc2[3].x * inv, acc2[3].y * inv);
        float4* op = (float4*)&out[(size_t)node * OUT_DIM + q * 8];
        op[0] = v0;
        op[1] = v1;
    }
}

// ---------------------------------------------------------------------------
extern "C" void kernel_launch(void* const* d_in, const int* in_sizes, int n_in,
                              void* d_out, int out_size, void* d_ws, size_t ws_size,
                              hipStream_t stream)
{
    const float* h      = (const float*)d_in[0];
    const float* fc_w   = (const float*)d_in[1];
    const float* attn_w = (const float*)d_in[2];
    const int*   src    = (const int*)d_in[3];
    const int*   dst    = (const int*)d_in[4];

    const int n_nodes = in_sizes[0] / IN_DIM;   // 50000
    const int n_edges = in_sizes[3];            // 800000
    const int nbuck   = (n_nodes + BUCK_NODES - 1) / BUCK_NODES;   // 391

    float* out = (float*)d_out;

    // workspace layout (all 4-byte types, 16B-aligned blocks)
    char* ws = (char*)d_ws;
    unsigned int* zb      = (unsigned int*)ws;                          // n_nodes*64 u32
    float* s_src          = (float*)(zb + (size_t)n_nodes * 64);        // n_nodes*4
    float* s_dst          = s_src + (size_t)n_nodes * N_HEADS;          // n_nodes*4
    int*   row_start      = (int*)(s_dst + (size_t)n_nodes * N_HEADS);  // n_nodes+1 (+pad)
    int*   bucket_fill    = row_start + n_nodes + 16;                   // nbuck
    int*   sorted_src     = bucket_fill + nbuck + 17;                   // n_edges
    unsigned int* scratch = (unsigned int*)(sorted_src + n_edges + 16); // nbuck*CAP
    unsigned short* wl_g  = (unsigned short*)(scratch + (size_t)nbuck * CAP); // 32768 bf16

    const int nA = (n_edges + CHUNK - 1) / CHUNK;        // 98 bucketA blocks
    const int nG = (n_nodes + 127) / 128;                // 391 gemm blocks

    // 1. setup: W prep + zero bucket_fill
    setup_kernel<<<128, 256, 0, stream>>>(fc_w, wl_g, bucket_fill, nbuck);

    // 2. FUSED: bucketA (CSR scatter) overlapped with MFMA GEMM
    fused_kernel<<<nA + nG, 512, 0, stream>>>(
        h, wl_g, attn_w, zb, s_src, s_dst, n_nodes,
        src, dst, bucket_fill, scratch, n_edges, nbuck, nA);

    // 3. bucket pass B: CSR finalize (pure LDS + dense writes)
    bucketB_kernel<<<nbuck, 256, 0, stream>>>(
        scratch, bucket_fill, row_start, sorted_src, n_nodes, nbuck, n_edges);

    // 4. fused single-pass softmax + aggregate, 2 consecutive nodes per wave
    {
        int waves = (n_nodes + 1) / 2;
        int blocks = (waves * 64 + 255) / 256;
        gather_kernel<<<blocks, 256, 0, stream>>>(
            sorted_src, row_start, zb, s_src, s_dst, out, n_nodes);
    }
}